// Round 8
// baseline (262.731 us; speedup 1.0000x reference)
//
#include <hip/hip_runtime.h>
#include <math.h>

#define NB 4096
#define NS 50
#define NH 64
#define NITEM 40000

typedef float f4 __attribute__((ext_vector_type(4)));

#define TOTAL4 (NB * NITEM / 4)     // 40,960,000 float4 (655 MB)
#define XCDW4  (TOTAL4 / 8)         // 5,120,000 float4 = 82 MB per-XCD window
#define ZSTRIDE (256 * 256)         // 256 zero-blocks/XCD x 256 thr = 1 MB sweep front

// Grid: 3072 blocks x 256. g = bid>>3 (group), xcd = bid&7 (measured HW
// round-robin block->XCD mapping, m09).
//   g%3 != 2 -> ZERO role (2048 blocks, 256 per XCD): the 256 blocks of XCD x
//               cooperatively sweep the CONTIGUOUS window [x*82MB, (x+1)*82MB)
//               with PLAIN float4 stores, grid-stride 1 MB. Theory: keeps each
//               XCD's L2 dirty-eviction stream compact/sequential (the runtime
//               fill's 6.6 TB/s geometry), vs 1.5-3.9 TB/s for all our
//               scattered/NT variants. Addressing is bijective regardless of
//               the real XCD mapping -> correctness never depends on it.
//   g%3 == 2 -> COMPUTE role (1024 blocks, 4 waves, one row b per wave):
//               lane i owns dim i (Ur[i,:] in 64 VGPRs), wave-uniform row
//               addresses, in-wave shfl softmax, probs -> d_ws.
// Roles interleave in dispatch order so stores start at t=0 and the ~20 us of
// compute hides under the write wall.
__global__ __launch_bounds__(256) void fused_xcd(
    const float* __restrict__ all_memory,   // [NB, NS, NH]
    const float* __restrict__ last_memory,  // [NB, NH]
    const float* __restrict__ Wr,           // [NH, NH]
    const float* __restrict__ Ur,           // [NH, NH]
    const float* __restrict__ Vr_w,         // [1, NH]
    float* __restrict__ out,                // [NB, NITEM]
    float* __restrict__ probs)              // [NB, NS] (workspace)
{
    const int bid = blockIdx.x;
    const int tid = (int)threadIdx.x;
    const int g = bid >> 3;
    const int xcd = bid & 7;

    if (g % 3 != 2) {
        // ---------------- zero role ----------------
        const int zslot = (g / 3) * 2 + (g % 3);        // 0..255 within XCD
        f4* w = (f4*)out + (long long)xcd * XCDW4;
        const f4 z = (f4)(0.0f);
        for (int i = zslot * 256 + tid; i < XCDW4; i += ZSTRIDE)
            w[i] = z;                                   // plain store (L2 path)
        return;
    }

    // ---------------- compute role: one wave per row ----------------
    const int lane = tid & 63;
    const int warp = __builtin_amdgcn_readfirstlane(tid >> 6);
    const int b = ((g / 3) * 8 + xcd) * 4 + warp;       // 0..4095, wave-uniform

    float ur[NH];
    {
        const float* urow = Ur + lane * NH;
        #pragma unroll
        for (int h = 0; h < NH; h += 4) {
            float4 u = *(const float4*)(urow + h);
            ur[h] = u.x; ur[h + 1] = u.y; ur[h + 2] = u.z; ur[h + 3] = u.w;
        }
    }
    float lm = 0.f;
    {
        const float* lrow = last_memory + b * NH;       // wave-uniform
        const float* wrow = Wr + lane * NH;
        #pragma unroll
        for (int h = 0; h < NH; h += 4) {
            float4 w = *(const float4*)(wrow + h);
            float4 l = *(const float4*)(lrow + h);
            lm += w.x * l.x + w.y * l.y + w.z * l.z + w.w * l.w;
        }
    }
    const float vw = Vr_w[lane];
    const float* am = all_memory + (long long)b * (NS * NH);

    float myscore = 0.f;
    for (int s = 0; s < NS; ++s) {
        const float* arow = am + s * NH;                // wave-uniform
        float v0 = 0.f, v1 = 0.f, v2 = 0.f, v3 = 0.f;
        #pragma unroll
        for (int h = 0; h < NH; h += 4) {
            float4 a = *(const float4*)(arow + h);
            v0 += a.x * ur[h];
            v1 += a.y * ur[h + 1];
            v2 += a.z * ur[h + 2];
            v3 += a.w * ur[h + 3];
        }
        // Vr_b dropped: constant score shift cancels in softmax.
        float t = tanhf(lm + ((v0 + v1) + (v2 + v3))) * vw;
        #pragma unroll
        for (int off = 32; off >= 1; off >>= 1)
            t += __shfl_xor(t, off, 64);
        myscore = (lane == s) ? t : myscore;
    }

    float sc = (lane < NS) ? myscore : -INFINITY;
    float m = sc;
    #pragma unroll
    for (int off = 32; off >= 1; off >>= 1)
        m = fmaxf(m, __shfl_xor(m, off, 64));
    float e = (lane < NS) ? expf(sc - m) : 0.f;
    float d = e;
    #pragma unroll
    for (int off = 32; off >= 1; off >>= 1)
        d += __shfl_xor(d, off, 64);
    if (lane < NS)
        probs[b * NS + lane] = e / d;
}

// One thread per (b, s): atomicAdd accumulates duplicate items exactly like
// the reference's .at[].add. Separate dispatch -> runs after all zeroing.
__global__ __launch_bounds__(256) void scatter_k(
    const float* __restrict__ probs,
    const int* __restrict__ seq,
    float* __restrict__ out)
{
    int t = blockIdx.x * 256 + threadIdx.x;
    if (t >= NB * NS) return;
    int b = t / NS;
    float p = probs[t];
    int item = seq[t];
    atomicAdd(out + (long long)b * NITEM + item, p);
}

extern "C" void kernel_launch(void* const* d_in, const int* in_sizes, int n_in,
                              void* d_out, int out_size, void* d_ws, size_t ws_size,
                              hipStream_t stream) {
    const float* all_memory  = (const float*)d_in[0];
    const float* last_memory = (const float*)d_in[1];
    const float* Wr          = (const float*)d_in[2];
    const float* Ur          = (const float*)d_in[3];
    const float* Vr_w        = (const float*)d_in[4];
    // d_in[5] = Vr_b: constant shift of all scores, cancels in softmax.
    const int*   seq         = (const int*)d_in[6];
    float* out   = (float*)d_out;
    float* probs = (float*)d_ws;   // NB*NS floats = 819,200 B

    fused_xcd<<<3072, 256, 0, stream>>>(all_memory, last_memory, Wr, Ur, Vr_w,
                                        out, probs);
    scatter_k<<<(NB * NS + 255) / 256, 256, 0, stream>>>(probs, seq, out);
}

// Round 9
// 256.795 us; speedup vs baseline: 1.0231x; 1.0231x over previous
//
#include <hip/hip_runtime.h>
#include <math.h>

#define NB 4096
#define NS 50
#define NH 64
#define NITEM 40000

typedef float f4 __attribute__((ext_vector_type(4)));

#define NZBLK 256                            // zero-role blocks (ALL resident)
#define TOTAL4 (NB * NITEM / 4)              // 40,960,000 float4 = 655 MB
#define ZSTRIDE (NZBLK * 256)                // 65,536 f4 = 1 MB sweep front

// Unified store-BW model from R1..R8:
//   per-block plain-store rate caps at ~29 GB/s; aggregate scales with
//   RESIDENT blocks only while the union of in-flight store addresses is one
//   compact sliding window. The 6.6 TB/s runtime fill = ~225 blocks, all
//   resident, global grid-stride (~1 MB front). Our slow variants all broke
//   one of those conditions (grid >> resident -> bimodal front, or NT, or
//   chunk scatter). This kernel replicates the fill geometry exactly:
//   NZBLK=256 zero blocks dispatched FIRST (bid<256 -> resident from t=0),
//   lockstep grid-stride sweep, plain float4 stores.
// Compute role (bids 256..1279): one wave per row b; lane i owns dim i
//   (Ur[i,:] in 64 VGPRs), wave-uniform row addresses -> scalar loads,
//   in-wave shfl softmax; probs -> d_ws. ~25 us, hides under the sweep.
__global__ __launch_bounds__(256) void fused_front(
    const float* __restrict__ all_memory,   // [NB, NS, NH]
    const float* __restrict__ last_memory,  // [NB, NH]
    const float* __restrict__ Wr,           // [NH, NH]
    const float* __restrict__ Ur,           // [NH, NH]
    const float* __restrict__ Vr_w,         // [1, NH]
    float* __restrict__ out,                // [NB, NITEM]
    float* __restrict__ probs)              // [NB, NS] (workspace)
{
    const int bid = blockIdx.x;
    const int tid = (int)threadIdx.x;

    if (bid < NZBLK) {
        // ---------------- zero role: lockstep compact-front sweep ----------
        f4* o4 = (f4*)out;
        const f4 z = (f4)(0.0f);
        for (int i = bid * 256 + tid; i < TOTAL4; i += ZSTRIDE)
            o4[i] = z;                       // plain store (fill-kernel path)
        return;
    }

    // ---------------- compute role: one wave per row ----------------
    const int lane = tid & 63;
    const int warp = __builtin_amdgcn_readfirstlane(tid >> 6);
    const int b = (bid - NZBLK) * 4 + warp;             // 0..4095, wave-uniform

    float ur[NH];
    {
        const float* urow = Ur + lane * NH;
        #pragma unroll
        for (int h = 0; h < NH; h += 4) {
            float4 u = *(const float4*)(urow + h);
            ur[h] = u.x; ur[h + 1] = u.y; ur[h + 2] = u.z; ur[h + 3] = u.w;
        }
    }
    float lm = 0.f;
    {
        const float* lrow = last_memory + b * NH;       // wave-uniform
        const float* wrow = Wr + lane * NH;
        #pragma unroll
        for (int h = 0; h < NH; h += 4) {
            float4 w = *(const float4*)(wrow + h);
            float4 l = *(const float4*)(lrow + h);
            lm += w.x * l.x + w.y * l.y + w.z * l.z + w.w * l.w;
        }
    }
    const float vw = Vr_w[lane];
    const float* am = all_memory + (long long)b * (NS * NH);

    float myscore = 0.f;
    for (int s = 0; s < NS; ++s) {
        const float* arow = am + s * NH;                // wave-uniform
        float v0 = 0.f, v1 = 0.f, v2 = 0.f, v3 = 0.f;
        #pragma unroll
        for (int h = 0; h < NH; h += 4) {
            float4 a = *(const float4*)(arow + h);
            v0 += a.x * ur[h];
            v1 += a.y * ur[h + 1];
            v2 += a.z * ur[h + 2];
            v3 += a.w * ur[h + 3];
        }
        // Vr_b dropped: constant score shift cancels in softmax.
        float t = tanhf(lm + ((v0 + v1) + (v2 + v3))) * vw;
        #pragma unroll
        for (int off = 32; off >= 1; off >>= 1)
            t += __shfl_xor(t, off, 64);
        myscore = (lane == s) ? t : myscore;
    }

    float sc = (lane < NS) ? myscore : -INFINITY;
    float m = sc;
    #pragma unroll
    for (int off = 32; off >= 1; off >>= 1)
        m = fmaxf(m, __shfl_xor(m, off, 64));
    float e = (lane < NS) ? expf(sc - m) : 0.f;
    float d = e;
    #pragma unroll
    for (int off = 32; off >= 1; off >>= 1)
        d += __shfl_xor(d, off, 64);
    if (lane < NS)
        probs[b * NS + lane] = e / d;
}

// One thread per (b, s): atomicAdd accumulates duplicate items exactly like
// the reference's .at[].add. Separate dispatch -> runs after all zeroing.
__global__ __launch_bounds__(256) void scatter_k(
    const float* __restrict__ probs,
    const int* __restrict__ seq,
    float* __restrict__ out)
{
    int t = blockIdx.x * 256 + threadIdx.x;
    if (t >= NB * NS) return;
    int b = t / NS;
    float p = probs[t];
    int item = seq[t];
    atomicAdd(out + (long long)b * NITEM + item, p);
}

extern "C" void kernel_launch(void* const* d_in, const int* in_sizes, int n_in,
                              void* d_out, int out_size, void* d_ws, size_t ws_size,
                              hipStream_t stream) {
    const float* all_memory  = (const float*)d_in[0];
    const float* last_memory = (const float*)d_in[1];
    const float* Wr          = (const float*)d_in[2];
    const float* Ur          = (const float*)d_in[3];
    const float* Vr_w        = (const float*)d_in[4];
    // d_in[5] = Vr_b: constant shift of all scores, cancels in softmax.
    const int*   seq         = (const int*)d_in[6];
    float* out   = (float*)d_out;
    float* probs = (float*)d_ws;   // NB*NS floats = 819,200 B

    fused_front<<<NZBLK + NB / 4, 256, 0, stream>>>(all_memory, last_memory,
                                                    Wr, Ur, Vr_w, out, probs);
    scatter_k<<<(NB * NS + 255) / 256, 256, 0, stream>>>(probs, seq, out);
}